// Round 1
// baseline (49.240 us; speedup 1.0000x reference)
//
#include <hip/hip_runtime.h>
#include <math.h>

#define FFT_N   4096
#define LOGN    12
#define THREADS 512
#define NBF     (FFT_N / 2)       // butterflies per stage
#define BPT     (NBF / THREADS)   // butterflies per thread per stage (4)

#define PI_F 3.14159265358979323846f

// XOR swizzle: bijective, involution. Preserves contiguous-block bank spread,
// breaks stride-2^k (incl. bit-reversal's stride-64) same-bank patterns.
__device__ __forceinline__ int SW(int i) { return i ^ ((i >> 6) & 63); }

__global__ __launch_bounds__(THREADS)
void fft4096_kernel(const float* __restrict__ xre, const float* __restrict__ xim,
                    float* __restrict__ yre, float* __restrict__ yim)
{
    __shared__ float2 sd[FFT_N];       // 32 KB, interleaved (re,im)
    __shared__ float2 tw[FFT_N / 2];   // 16 KB twiddle table

    const int tid = threadIdx.x;
    const int row = blockIdx.x;
    const float* xr = xre + (size_t)row * FFT_N;
    const float* xi = xim + (size_t)row * FFT_N;

    // Twiddle table: W[k] = exp(-2*pi*i*k/N), k in [0, N/2)
    for (int k = tid; k < FFT_N / 2; k += THREADS) {
        float s, c;
        sincosf(-2.0f * PI_F * (float)k / (float)FFT_N, &s, &c);
        tw[k] = make_float2(c, s);
    }

    // Coalesced float4 global load, bit-reversed scatter into LDS.
    const float4* xr4 = (const float4*)xr;
    const float4* xi4 = (const float4*)xi;
    #pragma unroll
    for (int it = 0; it < FFT_N / 4 / THREADS; ++it) {   // 2 iterations
        int t  = tid + it * THREADS;    // float4 index
        float4 r = xr4[t];
        float4 m = xi4[t];
        int i0 = 4 * t;
        int b0 = (int)(__brev((unsigned)(i0 + 0)) >> (32 - LOGN));
        int b1 = (int)(__brev((unsigned)(i0 + 1)) >> (32 - LOGN));
        int b2 = (int)(__brev((unsigned)(i0 + 2)) >> (32 - LOGN));
        int b3 = (int)(__brev((unsigned)(i0 + 3)) >> (32 - LOGN));
        sd[SW(b0)] = make_float2(r.x, m.x);
        sd[SW(b1)] = make_float2(r.y, m.y);
        sd[SW(b2)] = make_float2(r.z, m.z);
        sd[SW(b3)] = make_float2(r.w, m.w);
    }
    __syncthreads();

    // 12 radix-2 DIT stages.
    for (int st = 0; st < LOGN; ++st) {
        const int s = 1 << st;
        float2 va[BPT], vb[BPT], w[BPT];
        int p[BPT], q[BPT];
        #pragma unroll
        for (int b = 0; b < BPT; ++b) {
            int j  = tid + b * THREADS;          // butterfly id [0, 2048)
            int lo = j & (s - 1);
            p[b] = ((j >> st) << (st + 1)) | lo;
            q[b] = p[b] + s;
            w[b]  = tw[lo << (LOGN - 1 - st)];
            va[b] = sd[SW(p[b])];
            vb[b] = sd[SW(q[b])];
        }
        #pragma unroll
        for (int b = 0; b < BPT; ++b) {
            float tr = w[b].x * vb[b].x - w[b].y * vb[b].y;
            float ti = w[b].x * vb[b].y + w[b].y * vb[b].x;
            sd[SW(p[b])] = make_float2(va[b].x + tr, va[b].y + ti);
            sd[SW(q[b])] = make_float2(va[b].x - tr, va[b].y - ti);
        }
        __syncthreads();
    }

    // Linear LDS read, coalesced float4 global store (split planes).
    float* yr = yre + (size_t)row * FFT_N;
    float* yi = yim + (size_t)row * FFT_N;
    float4* yr4 = (float4*)yr;
    float4* yi4 = (float4*)yi;
    #pragma unroll
    for (int it = 0; it < FFT_N / 4 / THREADS; ++it) {
        int t  = tid + it * THREADS;
        int i0 = 4 * t;
        float2 e0 = sd[SW(i0 + 0)];
        float2 e1 = sd[SW(i0 + 1)];
        float2 e2 = sd[SW(i0 + 2)];
        float2 e3 = sd[SW(i0 + 3)];
        yr4[t] = make_float4(e0.x, e1.x, e2.x, e3.x);
        yi4[t] = make_float4(e0.y, e1.y, e2.y, e3.y);
    }
}

extern "C" void kernel_launch(void* const* d_in, const int* in_sizes, int n_in,
                              void* d_out, int out_size, void* d_ws, size_t ws_size,
                              hipStream_t stream) {
    const float* xre = (const float*)d_in[0];
    const float* xim = (const float*)d_in[1];
    const int total = in_sizes[0];          // B * N
    const int rows  = total / FFT_N;        // 2048
    float* yre = (float*)d_out;
    float* yim = yre + total;
    fft4096_kernel<<<dim3(rows), dim3(THREADS), 0, stream>>>(xre, xim, yre, yim);
}

// Round 2
// 27.322 us; speedup vs baseline: 1.8022x; 1.8022x over previous
//
#include <hip/hip_runtime.h>
#include <math.h>

#define FFT_N   4096
#define LOGN    12
#define THREADS 512
#define NEG2PI_N (-1.5339807878856412e-3f)   // -2*pi/4096

// XOR swizzle on float2 index: spreads every stage's stride-2^k access pattern
// to >= 4 evenly-distributed distinct addresses per pair-bank (free for b64).
__device__ __forceinline__ int SW2(int i) { return i ^ ((i >> 5) & 31); }

__device__ __forceinline__ float2 cmul(float2 a, float2 b) {
    return make_float2(a.x * b.x - a.y * b.y, a.x * b.y + a.y * b.x);
}

// DIT butterfly: b' = a - w*b ; a' = a + w*b
__device__ __forceinline__ void bfly(float2& a, float2& b, float2 w) {
    float tr = w.x * b.x - w.y * b.y;
    float ti = w.x * b.y + w.y * b.x;
    b = make_float2(a.x - tr, a.y - ti);
    a = make_float2(a.x + tr, a.y + ti);
}

// One radix-8 DIT stage = radix-2 stages ST, ST+1, ST+2 done in registers.
// Thread t owns group elements at positions base + k*s, k=0..7.
// All 7 level-twiddles derive from one sincos:
//   wc0 = W^(lo<<(9-ST)); wb0 = wc0^2; wa = wb0^2; rest are wc0*W8^k, wb0*(-i).
template<int ST, bool WRITE>
__device__ __forceinline__ void radix8_stage(float2* __restrict__ sd, int t, float2* v)
{
    const int s    = 1 << ST;
    const int lo   = t & (s - 1);
    const int base = ((t >> ST) << (ST + 3)) | lo;

    int addr[8];
    #pragma unroll
    for (int k = 0; k < 8; ++k) addr[k] = SW2(base + k * s);
    #pragma unroll
    for (int k = 0; k < 8; ++k) v[k] = sd[addr[k]];

    float ang = (float)(lo << (9 - ST)) * NEG2PI_N;
    float sn, cs;
    __sincosf(ang, &sn, &cs);
    const float2 wc0 = make_float2(cs, sn);
    const float2 wb0 = cmul(wc0, wc0);
    const float2 wa  = cmul(wb0, wb0);

    // level A (stride s): pairs (0,1)(2,3)(4,5)(6,7), twiddle wa
    bfly(v[0], v[1], wa); bfly(v[2], v[3], wa);
    bfly(v[4], v[5], wa); bfly(v[6], v[7], wa);

    // level B (stride 2s): pairs (0,2)(1,3)(4,6)(5,7), twiddles wb0, wb0*(-i)
    const float2 wb1 = make_float2(wb0.y, -wb0.x);
    bfly(v[0], v[2], wb0); bfly(v[1], v[3], wb1);
    bfly(v[4], v[6], wb0); bfly(v[5], v[7], wb1);

    // level C (stride 4s): pairs (k,k+4), twiddles wc0 * W8^k
    const float RH = 0.70710678118654752f;
    const float2 wc1 = cmul(wc0, make_float2(RH, -RH));
    const float2 wc2 = make_float2(wc0.y, -wc0.x);
    const float2 wc3 = cmul(wc0, make_float2(-RH, -RH));
    bfly(v[0], v[4], wc0); bfly(v[1], v[5], wc1);
    bfly(v[2], v[6], wc2); bfly(v[3], v[7], wc3);

    if (WRITE) {
        #pragma unroll
        for (int k = 0; k < 8; ++k) sd[addr[k]] = v[k];
    }
}

__global__ __launch_bounds__(THREADS)
void fft4096_r8(const float* __restrict__ xre, const float* __restrict__ xim,
                float* __restrict__ yre, float* __restrict__ yim)
{
    __shared__ float2 sd[FFT_N];   // 32 KB
    const int t = threadIdx.x;
    const size_t off = (size_t)blockIdx.x * FFT_N;

    // Coalesced float4 loads: thread t gets naturals {4t+j} and {2048+4t+j}.
    const float4* xr4 = (const float4*)(xre + off);
    const float4* xi4 = (const float4*)(xim + off);
    float4 r0 = xr4[t];
    float4 r1 = xr4[t + THREADS];
    float4 m0 = xi4[t];
    float4 m1 = xi4[t + THREADS];

    // brev12(4t+j) = (brev2(j)<<10) | (brev9(t)<<1); +2048 input -> +1 output.
    const int rb = (int)(__brev((unsigned)t) >> 23) << 1;
    sd[SW2(rb + (0 << 10))]     = make_float2(r0.x, m0.x);
    sd[SW2(rb + (2 << 10))]     = make_float2(r0.y, m0.y);
    sd[SW2(rb + (1 << 10))]     = make_float2(r0.z, m0.z);
    sd[SW2(rb + (3 << 10))]     = make_float2(r0.w, m0.w);
    sd[SW2(rb + 1)]             = make_float2(r1.x, m1.x);
    sd[SW2(rb + 1 + (2 << 10))] = make_float2(r1.y, m1.y);
    sd[SW2(rb + 1 + (1 << 10))] = make_float2(r1.z, m1.z);
    sd[SW2(rb + 1 + (3 << 10))] = make_float2(r1.w, m1.w);
    __syncthreads();

    float2 v[8];
    radix8_stage<0, true>(sd, t, v);  __syncthreads();
    radix8_stage<3, true>(sd, t, v);  __syncthreads();
    radix8_stage<6, true>(sd, t, v);  __syncthreads();
    radix8_stage<9, false>(sd, t, v); // outputs at positions t + 512k

    // Coalesced dword stores straight from registers (skips an LDS round-trip).
    float* yr = yre + off;
    float* yi = yim + off;
    #pragma unroll
    for (int k = 0; k < 8; ++k) {
        yr[t + (k << 9)] = v[k].x;
        yi[t + (k << 9)] = v[k].y;
    }
}

extern "C" void kernel_launch(void* const* d_in, const int* in_sizes, int n_in,
                              void* d_out, int out_size, void* d_ws, size_t ws_size,
                              hipStream_t stream) {
    const float* xre = (const float*)d_in[0];
    const float* xim = (const float*)d_in[1];
    const int total = in_sizes[0];          // B * N
    const int rows  = total / FFT_N;        // 2048
    float* yre = (float*)d_out;
    float* yim = yre + total;
    fft4096_r8<<<dim3(rows), dim3(THREADS), 0, stream>>>(xre, xim, yre, yim);
}